// Round 12
// baseline (322.142 us; speedup 1.0000x reference)
//
#include <hip/hip_runtime.h>
#include <hip/hip_bf16.h>
#include <hip/hip_fp16.h>

// GraphSAGE(2-layer, mean agg) + 3-layer MLP link predictor.
// N=100000, E=1.6M, E_PAIR=100000, D=128.
// Round 12: fused k_sage = mean-agg (into LDS) + MFMA transform. Kills the
// Agg global round-trip (50MB/layer) and overlaps gather with MFMA across
// the 2 resident blocks/CU. Predictor P1-split (R11) retained.

#define D 128
#define NR 512
#define PART_CHUNK 4096
#define LDA 40       // f16 elems per staged row (80B stride: 2-way banks = free)
#define LDAGG 136    // s_agg row stride f16 (272B)
#define LDH2 136     // s_h1 row stride f16

typedef _Float16 f16x8 __attribute__((ext_vector_type(8)));
typedef float f32x4 __attribute__((ext_vector_type(4)));

// ---------------- phase 1: region histogram ----------------
__global__ __launch_bounds__(256) void k_regcount(
    const int* __restrict__ dst, int* __restrict__ region_cnt, int e, int bound) {
    __shared__ int s[NR];
    for (int i = threadIdx.x; i < NR; i += 256) s[i] = 0;
    __syncthreads();
    for (int i = blockIdx.x * 256 + threadIdx.x; i < e; i += gridDim.x * 256)
        atomicAdd(&s[dst[i] / bound], 1);
    __syncthreads();
    for (int i = threadIdx.x; i < NR; i += 256)
        if (s[i]) atomicAdd(&region_cnt[i], s[i]);
}

__global__ void k_regbase(const int* __restrict__ region_cnt,
                          int* __restrict__ region_base, int* __restrict__ region_cursor) {
    if (threadIdx.x == 0 && blockIdx.x == 0) {
        int run = 0;
        for (int r = 0; r < NR; ++r) {
            region_base[r] = run; region_cursor[r] = run; run += region_cnt[r];
        }
        region_base[NR] = run;
    }
}

// ---------------- phase 2: partition edges into region-compacted packed list ----------------
__global__ __launch_bounds__(256) void k_regpart(
    const int* __restrict__ src, const int* __restrict__ dst,
    unsigned int* __restrict__ eout, int* __restrict__ region_cursor, int e, int bound) {
    __shared__ int s_cnt[NR];
    __shared__ int s_base[NR];
    for (int c0 = blockIdx.x * PART_CHUNK; c0 < e; c0 += gridDim.x * PART_CHUNK) {
        int cend = min(c0 + PART_CHUNK, e);
        for (int i = threadIdx.x; i < NR; i += 256) s_cnt[i] = 0;
        __syncthreads();
        for (int i = c0 + threadIdx.x; i < cend; i += 256)
            atomicAdd(&s_cnt[dst[i] / bound], 1);
        __syncthreads();
        for (int i = threadIdx.x; i < NR; i += 256)
            s_base[i] = s_cnt[i] ? atomicAdd(&region_cursor[i], s_cnt[i]) : 0;
        __syncthreads();
        for (int i = threadIdx.x; i < NR; i += 256) s_cnt[i] = 0;
        __syncthreads();
        for (int i = c0 + threadIdx.x; i < cend; i += 256) {
            int d = dst[i];
            int r = d / bound;
            unsigned int doff = (unsigned int)(d - r * bound);
            int p = atomicAdd(&s_cnt[r], 1);
            eout[s_base[r] + p] = (unsigned int)src[i] | (doff << 20);
        }
        __syncthreads();
    }
}

// ---------------- phase 3a: per-region degree count + scan -> row_off ----------------
__global__ __launch_bounds__(256) void k_rowoff(
    const unsigned int* __restrict__ ep, const int* __restrict__ region_base,
    int* __restrict__ row_off, int n, int bound) {
    int r = blockIdx.x;
    int rlo = r * bound;
    if (threadIdx.x == 0 && r == 0) row_off[n] = region_base[NR];
    if (rlo >= n) return;
    int nn = min(bound, n - rlo);
    __shared__ int s_deg[256];
    __shared__ int s_scan[256];
    if (threadIdx.x < 256) s_deg[threadIdx.x] = 0;
    __syncthreads();
    int beg = region_base[r], end = region_base[r + 1];
    for (int i = beg + threadIdx.x; i < end; i += 256)
        atomicAdd(&s_deg[ep[i] >> 20], 1);
    __syncthreads();
    int v = (threadIdx.x < nn) ? s_deg[threadIdx.x] : 0;
    s_scan[threadIdx.x] = v;
    __syncthreads();
    #pragma unroll
    for (int off = 1; off < 256; off <<= 1) {
        int add = (threadIdx.x >= off) ? s_scan[threadIdx.x - off] : 0;
        __syncthreads();
        s_scan[threadIdx.x] += add;
        __syncthreads();
    }
    if (threadIdx.x < nn)
        row_off[rlo + threadIdx.x] = region_base[r] +
            (threadIdx.x ? s_scan[threadIdx.x - 1] : 0);
}

// ---------------- phase 3b: per-region scatter with LDS cursor ----------------
__global__ __launch_bounds__(256) void k_scatter3(
    const unsigned int* __restrict__ ep, const int* __restrict__ region_base,
    const int* __restrict__ row_off, int* __restrict__ csr, int n, int bound) {
    int r = blockIdx.x;
    int rlo = r * bound;
    if (rlo >= n) return;
    int nn = min(bound, n - rlo);
    __shared__ int s_cur[256];
    __shared__ int s_ro[256];
    if (threadIdx.x < nn) {
        s_cur[threadIdx.x] = 0;
        s_ro[threadIdx.x] = row_off[rlo + threadIdx.x];
    }
    __syncthreads();
    int beg = region_base[r], end = region_base[r + 1];
    for (int i = beg + threadIdx.x; i < end; i += 256) {
        unsigned int v = ep[i];
        int doff = v >> 20;
        int srcn = v & 0xFFFFF;
        int p = atomicAdd(&s_cur[doff], 1);
        csr[s_ro[doff] + p] = srcn;
    }
}

// ---------------- f32 -> f16 converts ----------------
__global__ void k_cvt_f16(const float* __restrict__ src, _Float16* __restrict__ dst, int n8) {
    int i = blockIdx.x * 256 + threadIdx.x;
    if (i >= n8) return;
    const float4* s4 = (const float4*)src;
    float4 a = s4[2 * i], b = s4[2 * i + 1];
    f16x8 h;
    h[0] = (_Float16)a.x; h[1] = (_Float16)a.y; h[2] = (_Float16)a.z; h[3] = (_Float16)a.w;
    h[4] = (_Float16)b.x; h[5] = (_Float16)b.y; h[6] = (_Float16)b.z; h[7] = (_Float16)b.w;
    *(f16x8*)(dst + 8 * i) = h;
}

// weights: W1s,W1n,W2s,W2n linear; P1w repacked to P1cf[256][128]; P2w linear.
__global__ void k_cvt_weights(
    const float* __restrict__ W1s, const float* __restrict__ W1n,
    const float* __restrict__ W2s, const float* __restrict__ W2n,
    const float* __restrict__ P1w, const float* __restrict__ P2w,
    _Float16* __restrict__ Ws1f, _Float16* __restrict__ Wn1f,
    _Float16* __restrict__ Ws2f, _Float16* __restrict__ Wn2f,
    _Float16* __restrict__ P1cf, _Float16* __restrict__ P2wf) {
    int g = blockIdx.x * 256 + threadIdx.x;
    if (g >= 14336) return;
    const float* src; _Float16* dst; int off;
    if (g >= 8192 && g < 12288) {
        int u = g - 8192;
        int o = u >> 4, col = (u & 15) * 8;
        src = P1w + (size_t)(o & 127) * 256 + ((o >> 7) * 128) + col;
        float4 a = *(const float4*)src, b = *(const float4*)(src + 4);
        f16x8 h;
        h[0] = (_Float16)a.x; h[1] = (_Float16)a.y; h[2] = (_Float16)a.z; h[3] = (_Float16)a.w;
        h[4] = (_Float16)b.x; h[5] = (_Float16)b.y; h[6] = (_Float16)b.z; h[7] = (_Float16)b.w;
        *(f16x8*)(P1cf + (size_t)u * 8) = h;
        return;
    }
    if      (g <  2048) { src = W1s; dst = Ws1f; off = g; }
    else if (g <  4096) { src = W1n; dst = Wn1f; off = g - 2048; }
    else if (g <  6144) { src = W2s; dst = Ws2f; off = g - 4096; }
    else if (g <  8192) { src = W2n; dst = Wn2f; off = g - 6144; }
    else                { src = P2w; dst = P2wf; off = g - 12288; }
    const float4* s4 = (const float4*)src;
    float4 a = s4[2 * off], b = s4[2 * off + 1];
    f16x8 h;
    h[0] = (_Float16)a.x; h[1] = (_Float16)a.y; h[2] = (_Float16)a.z; h[3] = (_Float16)a.w;
    h[4] = (_Float16)b.x; h[5] = (_Float16)b.y; h[6] = (_Float16)b.z; h[7] = (_Float16)b.w;
    *(f16x8*)(dst + 8 * off) = h;
}

// ---------------- fused SAGE layer: agg->LDS, then MFMA transform ----------------
// 512 thr = 8 waves; tile 128 rows x 128 cols; wave (wr=w>>1, wc=w&1).
__global__ __launch_bounds__(512) void k_sage(
    const _Float16* __restrict__ Xf, const int* __restrict__ row_off,
    const int* __restrict__ csr,
    const _Float16* __restrict__ Wsf, const _Float16* __restrict__ Wnf,
    const float* __restrict__ bias, _Float16* __restrict__ outf,
    int n_rows, int do_relu) {
    __shared__ _Float16 s_agg[128 * LDAGG];
    __shared__ _Float16 s_a[2][128 * LDA];
    __shared__ _Float16 s_b[2][128 * LDA];
    int tid = threadIdx.x;
    int n0 = blockIdx.x * 128;

    // ---- phase 1: aggregate 128 rows into s_agg (32 groups x 4 nodes) ----
    {
        int grp = tid >> 4, l = tid & 15;
        #pragma unroll
        for (int it = 0; it < 4; ++it) {
            int r = grp + it * 32;
            int g = n0 + r;
            float acc[8] = {0.f, 0.f, 0.f, 0.f, 0.f, 0.f, 0.f, 0.f};
            float inv = 0.f;
            if (g < n_rows) {
                int beg = row_off[g], end = row_off[g + 1];
                int i = beg;
                for (; i + 4 <= end; i += 4) {
                    int s0 = csr[i], s1 = csr[i + 1], s2 = csr[i + 2], s3 = csr[i + 3];
                    f16x8 v0 = *(const f16x8*)(Xf + (size_t)s0 * D + l * 8);
                    f16x8 v1 = *(const f16x8*)(Xf + (size_t)s1 * D + l * 8);
                    f16x8 v2 = *(const f16x8*)(Xf + (size_t)s2 * D + l * 8);
                    f16x8 v3 = *(const f16x8*)(Xf + (size_t)s3 * D + l * 8);
                    #pragma unroll
                    for (int j = 0; j < 8; ++j)
                        acc[j] += ((float)v0[j] + (float)v1[j]) + ((float)v2[j] + (float)v3[j]);
                }
                for (; i < end; ++i) {
                    int s0 = csr[i];
                    f16x8 v0 = *(const f16x8*)(Xf + (size_t)s0 * D + l * 8);
                    #pragma unroll
                    for (int j = 0; j < 8; ++j) acc[j] += (float)v0[j];
                }
                inv = 1.0f / fmaxf((float)(end - beg), 1.0f);
            }
            f16x8 o;
            #pragma unroll
            for (int j = 0; j < 8; ++j) o[j] = (_Float16)(acc[j] * inv);
            *(f16x8*)(s_agg + r * LDAGG + l * 8) = o;
        }
    }

    // ---- phase 2: transform ----
    int w = tid >> 6, l = tid & 63;
    int wr = w >> 1, wc = w & 1;
    int l15 = l & 15, lk = l >> 4;
    int r = tid >> 2, q = tid & 3;
    int rstage = n0 + r; if (rstage >= n_rows) rstage = n_rows - 1;

    f32x4 acc[2][4];
    #pragma unroll
    for (int i = 0; i < 2; ++i)
        #pragma unroll
        for (int j = 0; j < 4; ++j) acc[i][j] = (f32x4){0.f, 0.f, 0.f, 0.f};

    int a_off = (wr * 32 + l15) * LDA + lk * 8;
    int agg_off = (wr * 32 + l15) * LDAGG + lk * 8;
    int b_off = (wc * 64 + l15) * LDA + lk * 8;
    int st_off = r * LDA + q * 8;

    // stage chunk 0 (X cols 0..31, Ws cols 0..31); sync also covers s_agg writes
    f16x8 av0 = *(const f16x8*)(Xf + (size_t)rstage * D + q * 8);
    f16x8 wv0 = *(const f16x8*)(Wsf + (size_t)r * D + q * 8);
    *(f16x8*)(&s_a[0][st_off]) = av0;
    *(f16x8*)(&s_b[0][st_off]) = wv0;
    __syncthreads();

    for (int c = 0; c < 8; ++c) {
        int b = c & 1;
        f16x8 av, wv;
        bool pf_a = (c < 3);
        if (c < 7) {
            int cn = c + 1;
            const _Float16* wsrc = (cn < 4) ? Wsf : Wnf;
            int kb = (cn & 3) * 32;
            if (pf_a)
                av = *(const f16x8*)(Xf + (size_t)rstage * D + kb + q * 8);
            wv = *(const f16x8*)(wsrc + (size_t)r * D + kb + q * 8);
        }
        f16x8 af[2], bf[4];
        if (c < 4) {
            af[0] = *(const f16x8*)(&s_a[b][a_off]);
            af[1] = *(const f16x8*)(&s_a[b][a_off + 16 * LDA]);
        } else {
            int kb = (c - 4) * 32;
            af[0] = *(const f16x8*)(s_agg + agg_off + kb);
            af[1] = *(const f16x8*)(s_agg + agg_off + 16 * LDAGG + kb);
        }
        #pragma unroll
        for (int j = 0; j < 4; ++j) bf[j] = *(const f16x8*)(&s_b[b][b_off + j * 16 * LDA]);
        #pragma unroll
        for (int i = 0; i < 2; ++i)
            #pragma unroll
            for (int j = 0; j < 4; ++j)
                acc[i][j] = __builtin_amdgcn_mfma_f32_16x16x32_f16(af[i], bf[j], acc[i][j], 0, 0, 0);
        if (c < 7) {
            if (pf_a) *(f16x8*)(&s_a[b ^ 1][st_off]) = av;
            *(f16x8*)(&s_b[b ^ 1][st_off]) = wv;
        }
        __syncthreads();
    }

    #pragma unroll
    for (int j = 0; j < 4; ++j) {
        int col = wc * 64 + j * 16 + l15;
        float bv = bias[col];
        #pragma unroll
        for (int i = 0; i < 2; ++i) {
            int rowb = n0 + wr * 32 + i * 16 + lk * 4;
            #pragma unroll
            for (int v = 0; v < 4; ++v) {
                int row = rowb + v;
                if (row < n_rows) {
                    float xv = acc[i][j][v] + bv;
                    if (do_relu) xv = fmaxf(xv, 0.f);
                    outf[(size_t)row * D + col] = (_Float16)xv;
                }
            }
        }
    }
}

// ---------------- k_pre: Pre[n][o] = sum_k h2[n][k] * P1cf[o][k], o in [0,256) ----------------
__global__ __launch_bounds__(512) void k_pre(
    const _Float16* __restrict__ Hf, const _Float16* __restrict__ P1cf,
    _Float16* __restrict__ Pre, int n_rows) {
    __shared__ _Float16 s_a[64 * LDA];
    __shared__ _Float16 s_b[256 * LDA];
    int tid = threadIdx.x;
    int w = tid >> 6, l = tid & 63;
    int wr = w >> 2, wc = w & 3;
    int l15 = l & 15, lk = l >> 4;
    int n0 = blockIdx.x * 64;

    f32x4 acc[2][4];
    #pragma unroll
    for (int i = 0; i < 2; ++i)
        #pragma unroll
        for (int j = 0; j < 4; ++j) acc[i][j] = (f32x4){0.f, 0.f, 0.f, 0.f};

    int a_off = (wr * 32 + l15) * LDA + lk * 8;

    for (int c = 0; c < 4; ++c) {
        int kb = c * 32;
        __syncthreads();
        if (tid < 256) {
            int r = tid >> 2, q = tid & 3;
            int rstage = n0 + r; if (rstage >= n_rows) rstage = n_rows - 1;
            *(f16x8*)(&s_a[r * LDA + q * 8]) =
                *(const f16x8*)(Hf + (size_t)rstage * D + kb + q * 8);
        }
        #pragma unroll
        for (int e = 0; e < 2; ++e) {
            int idx = tid + e * 512;
            int o = idx >> 2, q = idx & 3;
            *(f16x8*)(&s_b[o * LDA + q * 8]) =
                *(const f16x8*)(P1cf + (size_t)o * 128 + kb + q * 8);
        }
        __syncthreads();
        f16x8 af[2], bf[4];
        af[0] = *(const f16x8*)(&s_a[a_off]);
        af[1] = *(const f16x8*)(&s_a[a_off + 16 * LDA]);
        #pragma unroll
        for (int j = 0; j < 4; ++j)
            bf[j] = *(const f16x8*)(&s_b[(wc * 64 + j * 16 + l15) * LDA + lk * 8]);
        #pragma unroll
        for (int i = 0; i < 2; ++i)
            #pragma unroll
            for (int j = 0; j < 4; ++j)
                acc[i][j] = __builtin_amdgcn_mfma_f32_16x16x32_f16(af[i], bf[j], acc[i][j], 0, 0, 0);
    }

    #pragma unroll
    for (int j = 0; j < 4; ++j) {
        int col = wc * 64 + j * 16 + l15;
        #pragma unroll
        for (int i = 0; i < 2; ++i) {
            int rowb = n0 + wr * 32 + i * 16 + lk * 4;
            #pragma unroll
            for (int v = 0; v < 4; ++v) {
                int row = rowb + v;
                if (row < n_rows)
                    Pre[(size_t)row * 256 + col] = (_Float16)acc[i][j][v];
            }
        }
    }
}

// ---------------- fused predictor: gather Pre rows -> h1 -> P2 -> P3 ----------------
__global__ __launch_bounds__(256) void k_mlp(
    const _Float16* __restrict__ Pre,
    const int* __restrict__ pos_src, const int* __restrict__ pos_dst,
    const int* __restrict__ neg_src, const int* __restrict__ neg_dst,
    const float* __restrict__ P1b,
    const _Float16* __restrict__ P2wf, const float* __restrict__ P2b,
    const float* __restrict__ P3w, const float* __restrict__ P3b,
    float* __restrict__ out, int EP) {
    __shared__ _Float16 s_h1[64 * LDH2];
    __shared__ _Float16 s_b[2][128 * LDA];
    __shared__ float s_red[64 * 2];
    __shared__ int s_node[128];
    int tid = threadIdx.x;
    int w = tid >> 6, l = tid & 63;
    int wr = w >> 1, wc = w & 1;
    int l15 = l & 15, lk = l >> 4;
    int p0 = blockIdx.x * 64;
    int twoEP = 2 * EP;

    if (tid < 128) {
        int p = p0 + (tid & 63);
        if (p >= twoEP) p = twoEP - 1;
        int node;
        if (tid < 64) node = (p < EP) ? pos_src[p] : neg_src[p - EP];
        else          node = (p < EP) ? pos_dst[p] : neg_dst[p - EP];
        s_node[tid] = node;
    }
    __syncthreads();

    #pragma unroll
    for (int e = 0; e < 4; ++e) {
        int idx = tid + e * 256;
        int pr = idx >> 4, u = idx & 15;
        int sn = s_node[pr], dn = s_node[64 + pr];
        f16x8 a = *(const f16x8*)(Pre + (size_t)sn * 256 + u * 8);
        f16x8 b = *(const f16x8*)(Pre + (size_t)dn * 256 + 128 + u * 8);
        float4 b0 = *(const float4*)(P1b + u * 8);
        float4 b1 = *(const float4*)(P1b + u * 8 + 4);
        float bb[8] = {b0.x, b0.y, b0.z, b0.w, b1.x, b1.y, b1.z, b1.w};
        f16x8 h;
        #pragma unroll
        for (int j = 0; j < 8; ++j)
            h[j] = (_Float16)fmaxf((float)a[j] + (float)b[j] + bb[j], 0.f);
        *(f16x8*)(&s_h1[pr * LDH2 + u * 8]) = h;
    }
    #pragma unroll
    for (int e = 0; e < 2; ++e) {
        int idx = tid + e * 256;
        int o = idx >> 2, q = idx & 3;
        *(f16x8*)(&s_b[0][o * LDA + q * 8]) = *(const f16x8*)(P2wf + (size_t)o * D + q * 8);
    }
    __syncthreads();

    f32x4 acc2[2][4];
    #pragma unroll
    for (int i = 0; i < 2; ++i)
        #pragma unroll
        for (int j = 0; j < 4; ++j) acc2[i][j] = (f32x4){0.f, 0.f, 0.f, 0.f};

    for (int c = 0; c < 4; ++c) {
        int b = c & 1;
        f16x8 nw[2];
        if (c < 3) {
            #pragma unroll
            for (int e = 0; e < 2; ++e) {
                int idx = tid + e * 256;
                int o = idx >> 2, q = idx & 3;
                nw[e] = *(const f16x8*)(P2wf + (size_t)o * D + (c + 1) * 32 + q * 8);
            }
        }
        f16x8 af[2], bf[4];
        af[0] = *(const f16x8*)(&s_h1[(wr * 32 + l15) * LDH2 + c * 32 + lk * 8]);
        af[1] = *(const f16x8*)(&s_h1[(wr * 32 + 16 + l15) * LDH2 + c * 32 + lk * 8]);
        #pragma unroll
        for (int j = 0; j < 4; ++j)
            bf[j] = *(const f16x8*)(&s_b[b][(wc * 64 + j * 16 + l15) * LDA + lk * 8]);
        #pragma unroll
        for (int i = 0; i < 2; ++i)
            #pragma unroll
            for (int j = 0; j < 4; ++j)
                acc2[i][j] = __builtin_amdgcn_mfma_f32_16x16x32_f16(af[i], bf[j], acc2[i][j], 0, 0, 0);
        if (c < 3) {
            #pragma unroll
            for (int e = 0; e < 2; ++e) {
                int idx = tid + e * 256;
                int o = idx >> 2, q = idx & 3;
                *(f16x8*)(&s_b[b ^ 1][o * LDA + q * 8]) = nw[e];
            }
        }
        __syncthreads();
    }

    float b2v[4], pw[4];
    #pragma unroll
    for (int j = 0; j < 4; ++j) {
        int col = wc * 64 + j * 16 + l15;
        b2v[j] = P2b[col];
        pw[j] = P3w[col];
    }
    #pragma unroll
    for (int i = 0; i < 2; ++i) {
        #pragma unroll
        for (int v = 0; v < 4; ++v) {
            float s = 0.f;
            #pragma unroll
            for (int j = 0; j < 4; ++j)
                s += fmaxf(acc2[i][j][v] + b2v[j], 0.f) * pw[j];
            s += __shfl_xor(s, 1);
            s += __shfl_xor(s, 2);
            s += __shfl_xor(s, 4);
            s += __shfl_xor(s, 8);
            if (l15 == 0)
                s_red[(wr * 32 + i * 16 + lk * 4 + v) * 2 + wc] = s;
        }
    }
    __syncthreads();
    if (tid < 64) {
        int p = p0 + tid;
        if (p < twoEP) out[p] = s_red[tid * 2] + s_red[tid * 2 + 1] + P3b[0];
    }
}

static inline size_t align_up(size_t x, size_t a) { return (x + a - 1) & ~(a - 1); }

extern "C" void kernel_launch(void* const* d_in, const int* in_sizes, int n_in,
                              void* d_out, int out_size, void* d_ws, size_t ws_size,
                              hipStream_t stream) {
    const float* x        = (const float*)d_in[0];
    const int*   edge_src = (const int*)d_in[1];
    const int*   edge_dst = (const int*)d_in[2];
    const int*   pos_src  = (const int*)d_in[3];
    const int*   pos_dst  = (const int*)d_in[4];
    const int*   neg_src  = (const int*)d_in[5];
    const int*   neg_dst  = (const int*)d_in[6];
    const float* W1n = (const float*)d_in[7];
    const float* W1s = (const float*)d_in[8];
    const float* b1  = (const float*)d_in[9];
    const float* W2n = (const float*)d_in[10];
    const float* W2s = (const float*)d_in[11];
    const float* b2  = (const float*)d_in[12];
    const float* P1w = (const float*)d_in[13];
    const float* P1b = (const float*)d_in[14];
    const float* P2w = (const float*)d_in[15];
    const float* P2b = (const float*)d_in[16];
    const float* P3w = (const float*)d_in[17];
    const float* P3b = (const float*)d_in[18];
    float* out = (float*)d_out;

    const int N = in_sizes[0] / D;
    const int E = in_sizes[1];
    const int EP = in_sizes[3];
    const int bound = (N + NR - 1) / NR;   // nodes per region (196 < 256)

    char* ws = (char*)d_ws;
    size_t off = 0;
    int* row_off = (int*)(ws + off); off = align_up(off + (size_t)(N + 1) * 4, 256);
    int* regmeta = (int*)(ws + off); off = align_up(off + (size_t)(3 * NR + 8) * 4, 256);
    int* csr     = (int*)(ws + off); off = align_up(off + (size_t)E * 4, 256);
    unsigned int* epart = (unsigned int*)(ws + off); off = align_up(off + (size_t)E * 4, 256);
    _Float16* xf   = (_Float16*)(ws + off); off = align_up(off + (size_t)N * D * 2, 256);
    _Float16* aggf = (_Float16*)(ws + off); off = align_up(off + (size_t)N * D * 2, 256);
    _Float16* h1f  = (_Float16*)(ws + off); off = align_up(off + (size_t)N * D * 2, 256);
    _Float16* h2f  = (_Float16*)(ws + off); off = align_up(off + (size_t)N * D * 2, 256);
    _Float16* Ws1f = (_Float16*)(ws + off); off = align_up(off + (size_t)D * D * 2, 256);
    _Float16* Wn1f = (_Float16*)(ws + off); off = align_up(off + (size_t)D * D * 2, 256);
    _Float16* Ws2f = (_Float16*)(ws + off); off = align_up(off + (size_t)D * D * 2, 256);
    _Float16* Wn2f = (_Float16*)(ws + off); off = align_up(off + (size_t)D * D * 2, 256);
    _Float16* P1cf = (_Float16*)(ws + off); off = align_up(off + (size_t)2 * D * D * 2, 256);
    _Float16* P2wf = (_Float16*)(ws + off); off = align_up(off + (size_t)D * D * 2, 256);
    (void)ws_size;
    (void)aggf;

    // Pre[N][256] aliases xf+aggf (xf dead after layer 1, aggf unused)
    _Float16* Pre = xf;

    int* region_cnt    = regmeta;               // [NR]
    int* region_base   = regmeta + NR;          // [NR+1]
    int* region_cursor = regmeta + 2 * NR + 4;  // [NR]

    // --- CSR build: histogram, base, partition, rowoff, scatter ---
    hipMemsetAsync(region_cnt, 0, NR * 4, stream);
    k_regcount<<<128, 256, 0, stream>>>(edge_dst, region_cnt, E, bound);
    k_regbase<<<1, 1, 0, stream>>>(region_cnt, region_base, region_cursor);
    k_regpart<<<(E + PART_CHUNK - 1) / PART_CHUNK, 256, 0, stream>>>(
        edge_src, edge_dst, epart, region_cursor, E, bound);
    k_rowoff<<<NR, 256, 0, stream>>>(epart, region_base, row_off, N, bound);
    k_scatter3<<<NR, 256, 0, stream>>>(epart, region_base, row_off, csr, N, bound);

    // --- f16 conversions ---
    k_cvt_f16<<<(N * D / 8 + 255) / 256, 256, 0, stream>>>(x, xf, N * D / 8);
    k_cvt_weights<<<56, 256, 0, stream>>>(W1s, W1n, W2s, W2n, P1w, P2w,
                                          Ws1f, Wn1f, Ws2f, Wn2f, P1cf, P2wf);

    const int ngrid = (N + 127) / 128;
    const int pgrid = (2 * EP + 63) / 64;

    // --- fused layers ---
    k_sage<<<ngrid, 512, 0, stream>>>(xf, row_off, csr, Ws1f, Wn1f, b1, h1f, N, 1);
    k_sage<<<ngrid, 512, 0, stream>>>(h1f, row_off, csr, Ws2f, Wn2f, b2, h2f, N, 0);

    // --- predictor: dense P1 halves then pair gather + P2/P3 ---
    k_pre<<<(N + 63) / 64, 512, 0, stream>>>(h2f, P1cf, Pre, N);
    k_mlp<<<pgrid, 256, 0, stream>>>(Pre, pos_src, pos_dst, neg_src, neg_dst,
                                     P1b, P2wf, P2b, P3w, P3b, out, EP);
}

// Round 13
// 310.328 us; speedup vs baseline: 1.0381x; 1.0381x over previous
//
#include <hip/hip_runtime.h>
#include <hip/hip_bf16.h>
#include <hip/hip_fp16.h>

// GraphSAGE(2-layer, mean agg) + 3-layer MLP link predictor.
// N=100000, E=1.6M, E_PAIR=100000, D=128.
// Round 13: R11 split structure + (1) k_agg 8-deep unroll, (2) fused
// rowoff+scatter (edge slice in LDS, single epart pass), (3) fused setup
// kernel (cvt_x + cvt_weights + regcount in one launch).

#define D 128
#define NR 512
#define PART_CHUNK 4096
#define LDA 40       // f16 elems per staged row (80B stride: 2-way banks = free)
#define LDH2 136     // s_h1 row stride f16

typedef _Float16 f16x8 __attribute__((ext_vector_type(8)));
typedef float f32x4 __attribute__((ext_vector_type(4)));

__device__ __forceinline__ void cvt8(const float* src, _Float16* dst, int off8) {
    const float4* s4 = (const float4*)src;
    float4 a = s4[2 * off8], b = s4[2 * off8 + 1];
    f16x8 h;
    h[0] = (_Float16)a.x; h[1] = (_Float16)a.y; h[2] = (_Float16)a.z; h[3] = (_Float16)a.w;
    h[4] = (_Float16)b.x; h[5] = (_Float16)b.y; h[6] = (_Float16)b.z; h[7] = (_Float16)b.w;
    *(f16x8*)(dst + 8 * off8) = h;
}

// ---------------- k_setup: cvt_x | cvt_weights | region histogram ----------------
__global__ __launch_bounds__(256) void k_setup(
    const float* __restrict__ x, _Float16* __restrict__ xf, int n8, int nb_x,
    const float* __restrict__ W1s, const float* __restrict__ W1n,
    const float* __restrict__ W2s, const float* __restrict__ W2n,
    const float* __restrict__ P1w, const float* __restrict__ P2w,
    _Float16* __restrict__ Ws1f, _Float16* __restrict__ Wn1f,
    _Float16* __restrict__ Ws2f, _Float16* __restrict__ Wn2f,
    _Float16* __restrict__ P1cf, _Float16* __restrict__ P2wf,
    const int* __restrict__ dst, int* __restrict__ region_cnt, int e, int bound) {
    int b = blockIdx.x;
    if (b < nb_x) {
        int i = b * 256 + threadIdx.x;
        if (i < n8) cvt8(x, xf, i);
        return;
    }
    b -= nb_x;
    if (b < 56) {
        int g = b * 256 + threadIdx.x;
        if (g >= 14336) return;
        if (g >= 8192 && g < 12288) {
            int u = g - 8192;
            int o = u >> 4, col = (u & 15) * 8;
            const float* src = P1w + (size_t)(o & 127) * 256 + ((o >> 7) * 128) + col;
            float4 a = *(const float4*)src, bb = *(const float4*)(src + 4);
            f16x8 h;
            h[0] = (_Float16)a.x; h[1] = (_Float16)a.y; h[2] = (_Float16)a.z; h[3] = (_Float16)a.w;
            h[4] = (_Float16)bb.x; h[5] = (_Float16)bb.y; h[6] = (_Float16)bb.z; h[7] = (_Float16)bb.w;
            *(f16x8*)(P1cf + (size_t)u * 8) = h;
            return;
        }
        const float* src; _Float16* dstp; int off;
        if      (g <  2048) { src = W1s; dstp = Ws1f; off = g; }
        else if (g <  4096) { src = W1n; dstp = Wn1f; off = g - 2048; }
        else if (g <  6144) { src = W2s; dstp = Ws2f; off = g - 4096; }
        else if (g <  8192) { src = W2n; dstp = Wn2f; off = g - 6144; }
        else                { src = P2w; dstp = P2wf; off = g - 12288; }
        cvt8(src, dstp, off);
        return;
    }
    b -= 56;
    // region histogram: 128 blocks
    __shared__ int s[NR];
    for (int i = threadIdx.x; i < NR; i += 256) s[i] = 0;
    __syncthreads();
    for (int i = b * 256 + threadIdx.x; i < e; i += 128 * 256)
        atomicAdd(&s[dst[i] / bound], 1);
    __syncthreads();
    for (int i = threadIdx.x; i < NR; i += 256)
        if (s[i]) atomicAdd(&region_cnt[i], s[i]);
}

__global__ void k_regbase(const int* __restrict__ region_cnt,
                          int* __restrict__ region_base, int* __restrict__ region_cursor) {
    if (threadIdx.x == 0 && blockIdx.x == 0) {
        int run = 0;
        for (int r = 0; r < NR; ++r) {
            region_base[r] = run; region_cursor[r] = run; run += region_cnt[r];
        }
        region_base[NR] = run;
    }
}

// ---------------- partition edges into region-compacted packed list ----------------
__global__ __launch_bounds__(256) void k_regpart(
    const int* __restrict__ src, const int* __restrict__ dst,
    unsigned int* __restrict__ eout, int* __restrict__ region_cursor, int e, int bound) {
    __shared__ int s_cnt[NR];
    __shared__ int s_base[NR];
    for (int c0 = blockIdx.x * PART_CHUNK; c0 < e; c0 += gridDim.x * PART_CHUNK) {
        int cend = min(c0 + PART_CHUNK, e);
        for (int i = threadIdx.x; i < NR; i += 256) s_cnt[i] = 0;
        __syncthreads();
        for (int i = c0 + threadIdx.x; i < cend; i += 256)
            atomicAdd(&s_cnt[dst[i] / bound], 1);
        __syncthreads();
        for (int i = threadIdx.x; i < NR; i += 256)
            s_base[i] = s_cnt[i] ? atomicAdd(&region_cursor[i], s_cnt[i]) : 0;
        __syncthreads();
        for (int i = threadIdx.x; i < NR; i += 256) s_cnt[i] = 0;
        __syncthreads();
        for (int i = c0 + threadIdx.x; i < cend; i += 256) {
            int d = dst[i];
            int r = d / bound;
            unsigned int doff = (unsigned int)(d - r * bound);
            int p = atomicAdd(&s_cnt[r], 1);
            eout[s_base[r] + p] = (unsigned int)src[i] | (doff << 20);
        }
        __syncthreads();
    }
}

// ---------------- fused per-region rowoff + scatter (edges cached in LDS) ----------------
#define EMAX 4608
__global__ __launch_bounds__(256) void k_rowoff_scatter(
    const unsigned int* __restrict__ ep, const int* __restrict__ region_base,
    int* __restrict__ row_off, int* __restrict__ csr, int n, int bound) {
    int r = blockIdx.x;
    int rlo = r * bound;
    if (threadIdx.x == 0 && r == 0) row_off[n] = region_base[NR];
    if (rlo >= n) return;
    int nn = min(bound, n - rlo);
    __shared__ unsigned int s_e[EMAX];
    __shared__ int s_deg[256];
    __shared__ int s_scan[256];
    __shared__ int s_cur[256];
    int beg = region_base[r], end = region_base[r + 1];
    int cnt = end - beg;
    bool fit = (cnt <= EMAX);
    if (fit)
        for (int i = threadIdx.x; i < cnt; i += 256) s_e[i] = ep[beg + i];
    s_deg[threadIdx.x] = 0;
    __syncthreads();
    for (int i = threadIdx.x; i < cnt; i += 256)
        atomicAdd(&s_deg[(fit ? s_e[i] : ep[beg + i]) >> 20], 1);
    __syncthreads();
    int v = (threadIdx.x < nn) ? s_deg[threadIdx.x] : 0;
    s_scan[threadIdx.x] = v;
    __syncthreads();
    #pragma unroll
    for (int off = 1; off < 256; off <<= 1) {
        int add = (threadIdx.x >= off) ? s_scan[threadIdx.x - off] : 0;
        __syncthreads();
        s_scan[threadIdx.x] += add;
        __syncthreads();
    }
    int base = beg + (threadIdx.x ? s_scan[threadIdx.x - 1] : 0);
    s_cur[threadIdx.x] = base;
    if (threadIdx.x < nn) row_off[rlo + threadIdx.x] = base;
    __syncthreads();
    for (int i = threadIdx.x; i < cnt; i += 256) {
        unsigned int e2 = fit ? s_e[i] : ep[beg + i];
        int doff = e2 >> 20;
        int p = atomicAdd(&s_cur[doff], 1);
        csr[p] = e2 & 0xFFFFF;
    }
}

// ---------------- mean aggregation: 16-lane group per node, 8-deep ----------------
__global__ __launch_bounds__(256) void k_agg(
    const _Float16* __restrict__ Xf, const int* __restrict__ row_off,
    const int* __restrict__ csr, _Float16* __restrict__ Aggf, int n_nodes) {
    int g = blockIdx.x * 16 + (threadIdx.x >> 4);
    if (g >= n_nodes) return;
    int l = threadIdx.x & 15;
    int beg = row_off[g], end = row_off[g + 1];
    float acc[8] = {0.f, 0.f, 0.f, 0.f, 0.f, 0.f, 0.f, 0.f};
    int i = beg;
    for (; i + 8 <= end; i += 8) {
        int si[8];
        #pragma unroll
        for (int j = 0; j < 8; ++j) si[j] = csr[i + j];
        f16x8 vv[8];
        #pragma unroll
        for (int j = 0; j < 8; ++j)
            vv[j] = *(const f16x8*)(Xf + (size_t)si[j] * D + l * 8);
        #pragma unroll
        for (int j = 0; j < 8; ++j)
            #pragma unroll
            for (int k = 0; k < 8; ++k) acc[k] += (float)vv[j][k];
    }
    for (; i + 2 <= end; i += 2) {
        int s0 = csr[i], s1 = csr[i + 1];
        f16x8 v0 = *(const f16x8*)(Xf + (size_t)s0 * D + l * 8);
        f16x8 v1 = *(const f16x8*)(Xf + (size_t)s1 * D + l * 8);
        #pragma unroll
        for (int k = 0; k < 8; ++k) acc[k] += (float)v0[k] + (float)v1[k];
    }
    if (i < end) {
        int s0 = csr[i];
        f16x8 v0 = *(const f16x8*)(Xf + (size_t)s0 * D + l * 8);
        #pragma unroll
        for (int k = 0; k < 8; ++k) acc[k] += (float)v0[k];
    }
    float inv = 1.0f / fmaxf((float)(end - beg), 1.0f);
    f16x8 o;
    #pragma unroll
    for (int k = 0; k < 8; ++k) o[k] = (_Float16)(acc[k] * inv);
    *(f16x8*)(Aggf + (size_t)g * D + l * 8) = o;
}

// ---------------- layer transform (MFMA, double-buffered) ----------------
__global__ __launch_bounds__(512) void k_transform(
    const _Float16* __restrict__ Xf, const _Float16* __restrict__ Aggf,
    const _Float16* __restrict__ Wsf, const _Float16* __restrict__ Wnf,
    const float* __restrict__ bias, _Float16* __restrict__ outf,
    int n_rows, int do_relu) {
    __shared__ _Float16 s_a[2][128 * LDA];
    __shared__ _Float16 s_b[2][128 * LDA];
    int tid = threadIdx.x;
    int w = tid >> 6, l = tid & 63;
    int wr = w >> 1, wc = w & 1;
    int l15 = l & 15, lk = l >> 4;
    int n0 = blockIdx.x * 128;
    int r = tid >> 2, q = tid & 3;
    int rstage = n0 + r; if (rstage >= n_rows) rstage = n_rows - 1;

    f32x4 acc[2][4];
    #pragma unroll
    for (int i = 0; i < 2; ++i)
        #pragma unroll
        for (int j = 0; j < 4; ++j) acc[i][j] = (f32x4){0.f, 0.f, 0.f, 0.f};

    int a_off = (wr * 32 + l15) * LDA + lk * 8;
    int b_off = (wc * 64 + l15) * LDA + lk * 8;
    int st_off = r * LDA + q * 8;

    {
        f16x8 av = *(const f16x8*)(Xf + (size_t)rstage * D + q * 8);
        f16x8 wv = *(const f16x8*)(Wsf + (size_t)r * D + q * 8);
        *(f16x8*)(&s_a[0][st_off]) = av;
        *(f16x8*)(&s_b[0][st_off]) = wv;
    }
    __syncthreads();

    for (int c = 0; c < 8; ++c) {
        int b = c & 1;
        f16x8 av, wv;
        if (c < 7) {
            int cn = c + 1;
            const _Float16* asrc = (cn < 4) ? Xf : Aggf;
            const _Float16* wsrc = (cn < 4) ? Wsf : Wnf;
            int kb = (cn & 3) * 32;
            av = *(const f16x8*)(asrc + (size_t)rstage * D + kb + q * 8);
            wv = *(const f16x8*)(wsrc + (size_t)r * D + kb + q * 8);
        }
        f16x8 af[2], bf[4];
        af[0] = *(const f16x8*)(&s_a[b][a_off]);
        af[1] = *(const f16x8*)(&s_a[b][a_off + 16 * LDA]);
        #pragma unroll
        for (int j = 0; j < 4; ++j) bf[j] = *(const f16x8*)(&s_b[b][b_off + j * 16 * LDA]);
        #pragma unroll
        for (int i = 0; i < 2; ++i)
            #pragma unroll
            for (int j = 0; j < 4; ++j)
                acc[i][j] = __builtin_amdgcn_mfma_f32_16x16x32_f16(af[i], bf[j], acc[i][j], 0, 0, 0);
        if (c < 7) {
            *(f16x8*)(&s_a[b ^ 1][st_off]) = av;
            *(f16x8*)(&s_b[b ^ 1][st_off]) = wv;
        }
        __syncthreads();
    }

    #pragma unroll
    for (int j = 0; j < 4; ++j) {
        int col = wc * 64 + j * 16 + l15;
        float bv = bias[col];
        #pragma unroll
        for (int i = 0; i < 2; ++i) {
            int rowb = n0 + wr * 32 + i * 16 + lk * 4;
            #pragma unroll
            for (int v = 0; v < 4; ++v) {
                int row = rowb + v;
                if (row < n_rows) {
                    float xv = acc[i][j][v] + bv;
                    if (do_relu) xv = fmaxf(xv, 0.f);
                    outf[(size_t)row * D + col] = (_Float16)xv;
                }
            }
        }
    }
}

// ---------------- k_pre: Pre[n][o] = sum_k h2[n][k] * P1cf[o][k], o in [0,256) ----------------
__global__ __launch_bounds__(512) void k_pre(
    const _Float16* __restrict__ Hf, const _Float16* __restrict__ P1cf,
    _Float16* __restrict__ Pre, int n_rows) {
    __shared__ _Float16 s_a[64 * LDA];
    __shared__ _Float16 s_b[256 * LDA];
    int tid = threadIdx.x;
    int w = tid >> 6, l = tid & 63;
    int wr = w >> 2, wc = w & 3;
    int l15 = l & 15, lk = l >> 4;
    int n0 = blockIdx.x * 64;

    f32x4 acc[2][4];
    #pragma unroll
    for (int i = 0; i < 2; ++i)
        #pragma unroll
        for (int j = 0; j < 4; ++j) acc[i][j] = (f32x4){0.f, 0.f, 0.f, 0.f};

    int a_off = (wr * 32 + l15) * LDA + lk * 8;

    for (int c = 0; c < 4; ++c) {
        int kb = c * 32;
        __syncthreads();
        if (tid < 256) {
            int r = tid >> 2, q = tid & 3;
            int rstage = n0 + r; if (rstage >= n_rows) rstage = n_rows - 1;
            *(f16x8*)(&s_a[r * LDA + q * 8]) =
                *(const f16x8*)(Hf + (size_t)rstage * D + kb + q * 8);
        }
        #pragma unroll
        for (int e = 0; e < 2; ++e) {
            int idx = tid + e * 512;
            int o = idx >> 2, q = idx & 3;
            *(f16x8*)(&s_b[o * LDA + q * 8]) =
                *(const f16x8*)(P1cf + (size_t)o * 128 + kb + q * 8);
        }
        __syncthreads();
        f16x8 af[2], bf[4];
        af[0] = *(const f16x8*)(&s_a[a_off]);
        af[1] = *(const f16x8*)(&s_a[a_off + 16 * LDA]);
        #pragma unroll
        for (int j = 0; j < 4; ++j)
            bf[j] = *(const f16x8*)(&s_b[(wc * 64 + j * 16 + l15) * LDA + lk * 8]);
        #pragma unroll
        for (int i = 0; i < 2; ++i)
            #pragma unroll
            for (int j = 0; j < 4; ++j)
                acc[i][j] = __builtin_amdgcn_mfma_f32_16x16x32_f16(af[i], bf[j], acc[i][j], 0, 0, 0);
    }

    #pragma unroll
    for (int j = 0; j < 4; ++j) {
        int col = wc * 64 + j * 16 + l15;
        #pragma unroll
        for (int i = 0; i < 2; ++i) {
            int rowb = n0 + wr * 32 + i * 16 + lk * 4;
            #pragma unroll
            for (int v = 0; v < 4; ++v) {
                int row = rowb + v;
                if (row < n_rows)
                    Pre[(size_t)row * 256 + col] = (_Float16)acc[i][j][v];
            }
        }
    }
}

// ---------------- fused predictor: gather Pre rows -> h1 -> P2 -> P3 ----------------
__global__ __launch_bounds__(256) void k_mlp(
    const _Float16* __restrict__ Pre,
    const int* __restrict__ pos_src, const int* __restrict__ pos_dst,
    const int* __restrict__ neg_src, const int* __restrict__ neg_dst,
    const float* __restrict__ P1b,
    const _Float16* __restrict__ P2wf, const float* __restrict__ P2b,
    const float* __restrict__ P3w, const float* __restrict__ P3b,
    float* __restrict__ out, int EP) {
    __shared__ _Float16 s_h1[64 * LDH2];
    __shared__ _Float16 s_b[2][128 * LDA];
    __shared__ float s_red[64 * 2];
    __shared__ int s_node[128];
    int tid = threadIdx.x;
    int w = tid >> 6, l = tid & 63;
    int wr = w >> 1, wc = w & 1;
    int l15 = l & 15, lk = l >> 4;
    int p0 = blockIdx.x * 64;
    int twoEP = 2 * EP;

    if (tid < 128) {
        int p = p0 + (tid & 63);
        if (p >= twoEP) p = twoEP - 1;
        int node;
        if (tid < 64) node = (p < EP) ? pos_src[p] : neg_src[p - EP];
        else          node = (p < EP) ? pos_dst[p] : neg_dst[p - EP];
        s_node[tid] = node;
    }
    __syncthreads();

    #pragma unroll
    for (int e = 0; e < 4; ++e) {
        int idx = tid + e * 256;
        int pr = idx >> 4, u = idx & 15;
        int sn = s_node[pr], dn = s_node[64 + pr];
        f16x8 a = *(const f16x8*)(Pre + (size_t)sn * 256 + u * 8);
        f16x8 b = *(const f16x8*)(Pre + (size_t)dn * 256 + 128 + u * 8);
        float4 b0 = *(const float4*)(P1b + u * 8);
        float4 b1 = *(const float4*)(P1b + u * 8 + 4);
        float bb[8] = {b0.x, b0.y, b0.z, b0.w, b1.x, b1.y, b1.z, b1.w};
        f16x8 h;
        #pragma unroll
        for (int j = 0; j < 8; ++j)
            h[j] = (_Float16)fmaxf((float)a[j] + (float)b[j] + bb[j], 0.f);
        *(f16x8*)(&s_h1[pr * LDH2 + u * 8]) = h;
    }
    #pragma unroll
    for (int e = 0; e < 2; ++e) {
        int idx = tid + e * 256;
        int o = idx >> 2, q = idx & 3;
        *(f16x8*)(&s_b[0][o * LDA + q * 8]) = *(const f16x8*)(P2wf + (size_t)o * D + q * 8);
    }
    __syncthreads();

    f32x4 acc2[2][4];
    #pragma unroll
    for (int i = 0; i < 2; ++i)
        #pragma unroll
        for (int j = 0; j < 4; ++j) acc2[i][j] = (f32x4){0.f, 0.f, 0.f, 0.f};

    for (int c = 0; c < 4; ++c) {
        int b = c & 1;
        f16x8 nw[2];
        if (c < 3) {
            #pragma unroll
            for (int e = 0; e < 2; ++e) {
                int idx = tid + e * 256;
                int o = idx >> 2, q = idx & 3;
                nw[e] = *(const f16x8*)(P2wf + (size_t)o * D + (c + 1) * 32 + q * 8);
            }
        }
        f16x8 af[2], bf[4];
        af[0] = *(const f16x8*)(&s_h1[(wr * 32 + l15) * LDH2 + c * 32 + lk * 8]);
        af[1] = *(const f16x8*)(&s_h1[(wr * 32 + 16 + l15) * LDH2 + c * 32 + lk * 8]);
        #pragma unroll
        for (int j = 0; j < 4; ++j)
            bf[j] = *(const f16x8*)(&s_b[b][(wc * 64 + j * 16 + l15) * LDA + lk * 8]);
        #pragma unroll
        for (int i = 0; i < 2; ++i)
            #pragma unroll
            for (int j = 0; j < 4; ++j)
                acc2[i][j] = __builtin_amdgcn_mfma_f32_16x16x32_f16(af[i], bf[j], acc2[i][j], 0, 0, 0);
        if (c < 3) {
            #pragma unroll
            for (int e = 0; e < 2; ++e) {
                int idx = tid + e * 256;
                int o = idx >> 2, q = idx & 3;
                *(f16x8*)(&s_b[b ^ 1][o * LDA + q * 8]) = nw[e];
            }
        }
        __syncthreads();
    }

    float b2v[4], pw[4];
    #pragma unroll
    for (int j = 0; j < 4; ++j) {
        int col = wc * 64 + j * 16 + l15;
        b2v[j] = P2b[col];
        pw[j] = P3w[col];
    }
    #pragma unroll
    for (int i = 0; i < 2; ++i) {
        #pragma unroll
        for (int v = 0; v < 4; ++v) {
            float s = 0.f;
            #pragma unroll
            for (int j = 0; j < 4; ++j)
                s += fmaxf(acc2[i][j][v] + b2v[j], 0.f) * pw[j];
            s += __shfl_xor(s, 1);
            s += __shfl_xor(s, 2);
            s += __shfl_xor(s, 4);
            s += __shfl_xor(s, 8);
            if (l15 == 0)
                s_red[(wr * 32 + i * 16 + lk * 4 + v) * 2 + wc] = s;
        }
    }
    __syncthreads();
    if (tid < 64) {
        int p = p0 + tid;
        if (p < twoEP) out[p] = s_red[tid * 2] + s_red[tid * 2 + 1] + P3b[0];
    }
}

static inline size_t align_up(size_t x, size_t a) { return (x + a - 1) & ~(a - 1); }

extern "C" void kernel_launch(void* const* d_in, const int* in_sizes, int n_in,
                              void* d_out, int out_size, void* d_ws, size_t ws_size,
                              hipStream_t stream) {
    const float* x        = (const float*)d_in[0];
    const int*   edge_src = (const int*)d_in[1];
    const int*   edge_dst = (const int*)d_in[2];
    const int*   pos_src  = (const int*)d_in[3];
    const int*   pos_dst  = (const int*)d_in[4];
    const int*   neg_src  = (const int*)d_in[5];
    const int*   neg_dst  = (const int*)d_in[6];
    const float* W1n = (const float*)d_in[7];
    const float* W1s = (const float*)d_in[8];
    const float* b1  = (const float*)d_in[9];
    const float* W2n = (const float*)d_in[10];
    const float* W2s = (const float*)d_in[11];
    const float* b2  = (const float*)d_in[12];
    const float* P1w = (const float*)d_in[13];
    const float* P1b = (const float*)d_in[14];
    const float* P2w = (const float*)d_in[15];
    const float* P2b = (const float*)d_in[16];
    const float* P3w = (const float*)d_in[17];
    const float* P3b = (const float*)d_in[18];
    float* out = (float*)d_out;

    const int N = in_sizes[0] / D;
    const int E = in_sizes[1];
    const int EP = in_sizes[3];
    const int bound = (N + NR - 1) / NR;   // nodes per region (196 < 256)

    char* ws = (char*)d_ws;
    size_t off = 0;
    int* row_off = (int*)(ws + off); off = align_up(off + (size_t)(N + 1) * 4, 256);
    int* regmeta = (int*)(ws + off); off = align_up(off + (size_t)(3 * NR + 8) * 4, 256);
    int* csr     = (int*)(ws + off); off = align_up(off + (size_t)E * 4, 256);
    unsigned int* epart = (unsigned int*)(ws + off); off = align_up(off + (size_t)E * 4, 256);
    _Float16* xf   = (_Float16*)(ws + off); off = align_up(off + (size_t)N * D * 2, 256);
    _Float16* aggf = (_Float16*)(ws + off); off = align_up(off + (size_t)N * D * 2, 256);
    _Float16* h1f  = (_Float16*)(ws + off); off = align_up(off + (size_t)N * D * 2, 256);
    _Float16* h2f  = (_Float16*)(ws + off); off = align_up(off + (size_t)N * D * 2, 256);
    _Float16* Ws1f = (_Float16*)(ws + off); off = align_up(off + (size_t)D * D * 2, 256);
    _Float16* Wn1f = (_Float16*)(ws + off); off = align_up(off + (size_t)D * D * 2, 256);
    _Float16* Ws2f = (_Float16*)(ws + off); off = align_up(off + (size_t)D * D * 2, 256);
    _Float16* Wn2f = (_Float16*)(ws + off); off = align_up(off + (size_t)D * D * 2, 256);
    _Float16* P1cf = (_Float16*)(ws + off); off = align_up(off + (size_t)2 * D * D * 2, 256);
    _Float16* P2wf = (_Float16*)(ws + off); off = align_up(off + (size_t)D * D * 2, 256);
    (void)ws_size;

    // Pre[N][256] aliases xf+aggf (xf dead after layer 1, aggf dead after layer 2)
    _Float16* Pre = xf;

    int* region_cnt    = regmeta;               // [NR]
    int* region_base   = regmeta + NR;          // [NR+1]
    int* region_cursor = regmeta + 2 * NR + 4;  // [NR]

    const int n8 = N * D / 8;
    const int nb_x = (n8 + 255) / 256;

    // --- setup: cvt_x + cvt_weights + region histogram (one launch) ---
    hipMemsetAsync(region_cnt, 0, NR * 4, stream);
    k_setup<<<nb_x + 56 + 128, 256, 0, stream>>>(
        x, xf, n8, nb_x, W1s, W1n, W2s, W2n, P1w, P2w,
        Ws1f, Wn1f, Ws2f, Wn2f, P1cf, P2wf,
        edge_dst, region_cnt, E, bound);
    k_regbase<<<1, 1, 0, stream>>>(region_cnt, region_base, region_cursor);
    k_regpart<<<(E + PART_CHUNK - 1) / PART_CHUNK, 256, 0, stream>>>(
        edge_src, edge_dst, epart, region_cursor, E, bound);
    k_rowoff_scatter<<<NR, 256, 0, stream>>>(epart, region_base, row_off, csr, N, bound);

    const int ngrid = (N + 127) / 128;
    const int pgrid = (2 * EP + 63) / 64;

    // --- layer 1 ---
    k_agg<<<(N + 15) / 16, 256, 0, stream>>>(xf, row_off, csr, aggf, N);
    k_transform<<<ngrid, 512, 0, stream>>>(xf, aggf, Ws1f, Wn1f, b1, h1f, N, 1);
    // --- layer 2 ---
    k_agg<<<(N + 15) / 16, 256, 0, stream>>>(h1f, row_off, csr, aggf, N);
    k_transform<<<ngrid, 512, 0, stream>>>(h1f, aggf, Ws2f, Wn2f, b2, h2f, N, 0);

    // --- predictor: dense P1 halves then pair gather + P2/P3 ---
    k_pre<<<(N + 63) / 64, 512, 0, stream>>>(h2f, P1cf, Pre, N);
    k_mlp<<<pgrid, 256, 0, stream>>>(Pre, pos_src, pos_dst, neg_src, neg_dst,
                                     P1b, P2wf, P2b, P3w, P3b, out, EP);
}

// Round 14
// 303.574 us; speedup vs baseline: 1.0612x; 1.0222x over previous
//
#include <hip/hip_runtime.h>
#include <hip/hip_bf16.h>
#include <hip/hip_fp16.h>

// GraphSAGE(2-layer, mean agg) + 3-layer MLP link predictor.
// N=100000, E=1.6M, E_PAIR=100000, D=128.
// Round 14: (1) k_pre fused into layer-2 transform (h2 stays in LDS, never
// globalized); (2) k_regbase parallel LDS scan (was 1-thread x 512 global RTs);
// (3) k_regpart per-block-span reservation (less epart write-amp).

#define D 128
#define NR 512
#define LDA 40       // f16 elems per staged row (80B stride: 2-way banks = free)
#define LDAGG 136    // s_h2 row stride f16
#define LDH2 136     // s_h1 row stride f16

typedef _Float16 f16x8 __attribute__((ext_vector_type(8)));
typedef float f32x4 __attribute__((ext_vector_type(4)));

__device__ __forceinline__ void cvt8(const float* src, _Float16* dst, int off8) {
    const float4* s4 = (const float4*)src;
    float4 a = s4[2 * off8], b = s4[2 * off8 + 1];
    f16x8 h;
    h[0] = (_Float16)a.x; h[1] = (_Float16)a.y; h[2] = (_Float16)a.z; h[3] = (_Float16)a.w;
    h[4] = (_Float16)b.x; h[5] = (_Float16)b.y; h[6] = (_Float16)b.z; h[7] = (_Float16)b.w;
    *(f16x8*)(dst + 8 * off8) = h;
}

// ---------------- k_setup: cvt_x | cvt_weights | region histogram ----------------
__global__ __launch_bounds__(256) void k_setup(
    const float* __restrict__ x, _Float16* __restrict__ xf, int n8, int nb_x,
    const float* __restrict__ W1s, const float* __restrict__ W1n,
    const float* __restrict__ W2s, const float* __restrict__ W2n,
    const float* __restrict__ P1w, const float* __restrict__ P2w,
    _Float16* __restrict__ Ws1f, _Float16* __restrict__ Wn1f,
    _Float16* __restrict__ Ws2f, _Float16* __restrict__ Wn2f,
    _Float16* __restrict__ P1cf, _Float16* __restrict__ P2wf,
    const int* __restrict__ dst, int* __restrict__ region_cnt, int e, int bound) {
    int b = blockIdx.x;
    if (b < nb_x) {
        int i = b * 256 + threadIdx.x;
        if (i < n8) cvt8(x, xf, i);
        return;
    }
    b -= nb_x;
    if (b < 56) {
        int g = b * 256 + threadIdx.x;
        if (g >= 14336) return;
        if (g >= 8192 && g < 12288) {
            int u = g - 8192;
            int o = u >> 4, col = (u & 15) * 8;
            const float* src = P1w + (size_t)(o & 127) * 256 + ((o >> 7) * 128) + col;
            float4 a = *(const float4*)src, bb = *(const float4*)(src + 4);
            f16x8 h;
            h[0] = (_Float16)a.x; h[1] = (_Float16)a.y; h[2] = (_Float16)a.z; h[3] = (_Float16)a.w;
            h[4] = (_Float16)bb.x; h[5] = (_Float16)bb.y; h[6] = (_Float16)bb.z; h[7] = (_Float16)bb.w;
            *(f16x8*)(P1cf + (size_t)u * 8) = h;
            return;
        }
        const float* src; _Float16* dstp; int off;
        if      (g <  2048) { src = W1s; dstp = Ws1f; off = g; }
        else if (g <  4096) { src = W1n; dstp = Wn1f; off = g - 2048; }
        else if (g <  6144) { src = W2s; dstp = Ws2f; off = g - 4096; }
        else if (g <  8192) { src = W2n; dstp = Wn2f; off = g - 6144; }
        else                { src = P2w; dstp = P2wf; off = g - 12288; }
        cvt8(src, dstp, off);
        return;
    }
    b -= 56;
    __shared__ int s[NR];
    for (int i = threadIdx.x; i < NR; i += 256) s[i] = 0;
    __syncthreads();
    for (int i = b * 256 + threadIdx.x; i < e; i += 128 * 256)
        atomicAdd(&s[dst[i] / bound], 1);
    __syncthreads();
    for (int i = threadIdx.x; i < NR; i += 256)
        if (s[i]) atomicAdd(&region_cnt[i], s[i]);
}

// ---------------- parallel exclusive scan of region counts ----------------
__global__ __launch_bounds__(NR) void k_regbase(
    const int* __restrict__ region_cnt,
    int* __restrict__ region_base, int* __restrict__ region_cursor) {
    __shared__ int s[NR];
    int t = threadIdx.x;
    int v = region_cnt[t];
    s[t] = v;
    __syncthreads();
    #pragma unroll
    for (int off = 1; off < NR; off <<= 1) {
        int add = (t >= off) ? s[t - off] : 0;
        __syncthreads();
        s[t] += add;
        __syncthreads();
    }
    int ex = s[t] - v;
    region_base[t] = ex;
    region_cursor[t] = ex;
    if (t == NR - 1) region_base[NR] = s[t];
}

// ---------------- partition edges (per-block span reservation) ----------------
__global__ __launch_bounds__(256) void k_regpart(
    const int* __restrict__ src, const int* __restrict__ dst,
    unsigned int* __restrict__ eout, int* __restrict__ region_cursor, int e, int bound) {
    __shared__ int s_cnt[NR];
    __shared__ int s_base[NR];
    int per = (e + gridDim.x - 1) / gridDim.x;
    int beg = blockIdx.x * per;
    int end = min(beg + per, e);
    for (int i = threadIdx.x; i < NR; i += 256) s_cnt[i] = 0;
    __syncthreads();
    for (int i = beg + threadIdx.x; i < end; i += 256)
        atomicAdd(&s_cnt[dst[i] / bound], 1);
    __syncthreads();
    for (int i = threadIdx.x; i < NR; i += 256)
        s_base[i] = s_cnt[i] ? atomicAdd(&region_cursor[i], s_cnt[i]) : 0;
    __syncthreads();
    for (int i = threadIdx.x; i < NR; i += 256) s_cnt[i] = 0;
    __syncthreads();
    for (int i = beg + threadIdx.x; i < end; i += 256) {
        int d = dst[i];
        int r = d / bound;
        unsigned int doff = (unsigned int)(d - r * bound);
        int p = atomicAdd(&s_cnt[r], 1);
        eout[s_base[r] + p] = (unsigned int)src[i] | (doff << 20);
    }
}

// ---------------- fused per-region rowoff + scatter ----------------
#define EMAX 4608
__global__ __launch_bounds__(256) void k_rowoff_scatter(
    const unsigned int* __restrict__ ep, const int* __restrict__ region_base,
    int* __restrict__ row_off, int* __restrict__ csr, int n, int bound) {
    int r = blockIdx.x;
    int rlo = r * bound;
    if (threadIdx.x == 0 && r == 0) row_off[n] = region_base[NR];
    if (rlo >= n) return;
    int nn = min(bound, n - rlo);
    __shared__ unsigned int s_e[EMAX];
    __shared__ int s_deg[256];
    __shared__ int s_scan[256];
    __shared__ int s_cur[256];
    int beg = region_base[r], end = region_base[r + 1];
    int cnt = end - beg;
    bool fit = (cnt <= EMAX);
    if (fit)
        for (int i = threadIdx.x; i < cnt; i += 256) s_e[i] = ep[beg + i];
    s_deg[threadIdx.x] = 0;
    __syncthreads();
    for (int i = threadIdx.x; i < cnt; i += 256)
        atomicAdd(&s_deg[(fit ? s_e[i] : ep[beg + i]) >> 20], 1);
    __syncthreads();
    int v = (threadIdx.x < nn) ? s_deg[threadIdx.x] : 0;
    s_scan[threadIdx.x] = v;
    __syncthreads();
    #pragma unroll
    for (int off = 1; off < 256; off <<= 1) {
        int add = (threadIdx.x >= off) ? s_scan[threadIdx.x - off] : 0;
        __syncthreads();
        s_scan[threadIdx.x] += add;
        __syncthreads();
    }
    int base = beg + (threadIdx.x ? s_scan[threadIdx.x - 1] : 0);
    s_cur[threadIdx.x] = base;
    if (threadIdx.x < nn) row_off[rlo + threadIdx.x] = base;
    __syncthreads();
    for (int i = threadIdx.x; i < cnt; i += 256) {
        unsigned int e2 = fit ? s_e[i] : ep[beg + i];
        int doff = e2 >> 20;
        int p = atomicAdd(&s_cur[doff], 1);
        csr[p] = e2 & 0xFFFFF;
    }
}

// ---------------- mean aggregation: 16-lane group per node ----------------
__global__ __launch_bounds__(256) void k_agg(
    const _Float16* __restrict__ Xf, const int* __restrict__ row_off,
    const int* __restrict__ csr, _Float16* __restrict__ Aggf, int n_nodes) {
    int g = blockIdx.x * 16 + (threadIdx.x >> 4);
    if (g >= n_nodes) return;
    int l = threadIdx.x & 15;
    int beg = row_off[g], end = row_off[g + 1];
    float acc[8] = {0.f, 0.f, 0.f, 0.f, 0.f, 0.f, 0.f, 0.f};
    int i = beg;
    for (; i + 8 <= end; i += 8) {
        int si[8];
        #pragma unroll
        for (int j = 0; j < 8; ++j) si[j] = csr[i + j];
        f16x8 vv[8];
        #pragma unroll
        for (int j = 0; j < 8; ++j)
            vv[j] = *(const f16x8*)(Xf + (size_t)si[j] * D + l * 8);
        #pragma unroll
        for (int j = 0; j < 8; ++j)
            #pragma unroll
            for (int k = 0; k < 8; ++k) acc[k] += (float)vv[j][k];
    }
    for (; i + 2 <= end; i += 2) {
        int s0 = csr[i], s1 = csr[i + 1];
        f16x8 v0 = *(const f16x8*)(Xf + (size_t)s0 * D + l * 8);
        f16x8 v1 = *(const f16x8*)(Xf + (size_t)s1 * D + l * 8);
        #pragma unroll
        for (int k = 0; k < 8; ++k) acc[k] += (float)v0[k] + (float)v1[k];
    }
    if (i < end) {
        int s0 = csr[i];
        f16x8 v0 = *(const f16x8*)(Xf + (size_t)s0 * D + l * 8);
        #pragma unroll
        for (int k = 0; k < 8; ++k) acc[k] += (float)v0[k];
    }
    float inv = 1.0f / fmaxf((float)(end - beg), 1.0f);
    f16x8 o;
    #pragma unroll
    for (int k = 0; k < 8; ++k) o[k] = (_Float16)(acc[k] * inv);
    *(f16x8*)(Aggf + (size_t)g * D + l * 8) = o;
}

// ---------------- layer-1 transform (MFMA, double-buffered, relu) ----------------
__global__ __launch_bounds__(512) void k_transform(
    const _Float16* __restrict__ Xf, const _Float16* __restrict__ Aggf,
    const _Float16* __restrict__ Wsf, const _Float16* __restrict__ Wnf,
    const float* __restrict__ bias, _Float16* __restrict__ outf, int n_rows) {
    __shared__ _Float16 s_a[2][128 * LDA];
    __shared__ _Float16 s_b[2][128 * LDA];
    int tid = threadIdx.x;
    int w = tid >> 6, l = tid & 63;
    int wr = w >> 1, wc = w & 1;
    int l15 = l & 15, lk = l >> 4;
    int n0 = blockIdx.x * 128;
    int r = tid >> 2, q = tid & 3;
    int rstage = n0 + r; if (rstage >= n_rows) rstage = n_rows - 1;

    f32x4 acc[2][4];
    #pragma unroll
    for (int i = 0; i < 2; ++i)
        #pragma unroll
        for (int j = 0; j < 4; ++j) acc[i][j] = (f32x4){0.f, 0.f, 0.f, 0.f};

    int a_off = (wr * 32 + l15) * LDA + lk * 8;
    int b_off = (wc * 64 + l15) * LDA + lk * 8;
    int st_off = r * LDA + q * 8;

    {
        f16x8 av = *(const f16x8*)(Xf + (size_t)rstage * D + q * 8);
        f16x8 wv = *(const f16x8*)(Wsf + (size_t)r * D + q * 8);
        *(f16x8*)(&s_a[0][st_off]) = av;
        *(f16x8*)(&s_b[0][st_off]) = wv;
    }
    __syncthreads();

    for (int c = 0; c < 8; ++c) {
        int b = c & 1;
        f16x8 av, wv;
        if (c < 7) {
            int cn = c + 1;
            const _Float16* asrc = (cn < 4) ? Xf : Aggf;
            const _Float16* wsrc = (cn < 4) ? Wsf : Wnf;
            int kb = (cn & 3) * 32;
            av = *(const f16x8*)(asrc + (size_t)rstage * D + kb + q * 8);
            wv = *(const f16x8*)(wsrc + (size_t)r * D + kb + q * 8);
        }
        f16x8 af[2], bf[4];
        af[0] = *(const f16x8*)(&s_a[b][a_off]);
        af[1] = *(const f16x8*)(&s_a[b][a_off + 16 * LDA]);
        #pragma unroll
        for (int j = 0; j < 4; ++j) bf[j] = *(const f16x8*)(&s_b[b][b_off + j * 16 * LDA]);
        #pragma unroll
        for (int i = 0; i < 2; ++i)
            #pragma unroll
            for (int j = 0; j < 4; ++j)
                acc[i][j] = __builtin_amdgcn_mfma_f32_16x16x32_f16(af[i], bf[j], acc[i][j], 0, 0, 0);
        if (c < 7) {
            *(f16x8*)(&s_a[b ^ 1][st_off]) = av;
            *(f16x8*)(&s_b[b ^ 1][st_off]) = wv;
        }
        __syncthreads();
    }

    #pragma unroll
    for (int j = 0; j < 4; ++j) {
        int col = wc * 64 + j * 16 + l15;
        float bv = bias[col];
        #pragma unroll
        for (int i = 0; i < 2; ++i) {
            int rowb = n0 + wr * 32 + i * 16 + lk * 4;
            #pragma unroll
            for (int v = 0; v < 4; ++v) {
                int row = rowb + v;
                if (row < n_rows)
                    outf[(size_t)row * D + col] = (_Float16)fmaxf(acc[i][j][v] + bv, 0.f);
            }
        }
    }
}

// ---------------- layer-2 transform fused with Pre GEMM ----------------
// phase1: h2 tile (128x128) into s_h2 (LDS, no relu, no global write)
// phase2: Pre[tile rows][256] = s_h2 @ P1cf^T, written to global.
__global__ __launch_bounds__(512) void k_transform_pre(
    const _Float16* __restrict__ Xf, const _Float16* __restrict__ Aggf,
    const _Float16* __restrict__ Wsf, const _Float16* __restrict__ Wnf,
    const float* __restrict__ bias, const _Float16* __restrict__ P1cf,
    _Float16* __restrict__ Pre, int n_rows) {
    __shared__ _Float16 s_a[2][128 * LDA];
    __shared__ _Float16 s_b[2][128 * LDA];
    __shared__ _Float16 s_h2[128 * LDAGG];
    int tid = threadIdx.x;
    int w = tid >> 6, l = tid & 63;
    int l15 = l & 15, lk = l >> 4;
    int n0 = blockIdx.x * 128;
    int r = tid >> 2, q = tid & 3;
    int rstage = n0 + r; if (rstage >= n_rows) rstage = n_rows - 1;

    // ---- phase 1: h2 tile ----
    {
        int wr = w >> 1, wc = w & 1;
        f32x4 acc[2][4];
        #pragma unroll
        for (int i = 0; i < 2; ++i)
            #pragma unroll
            for (int j = 0; j < 4; ++j) acc[i][j] = (f32x4){0.f, 0.f, 0.f, 0.f};

        int a_off = (wr * 32 + l15) * LDA + lk * 8;
        int b_off = (wc * 64 + l15) * LDA + lk * 8;
        int st_off = r * LDA + q * 8;

        f16x8 av0 = *(const f16x8*)(Xf + (size_t)rstage * D + q * 8);
        f16x8 wv0 = *(const f16x8*)(Wsf + (size_t)r * D + q * 8);
        *(f16x8*)(&s_a[0][st_off]) = av0;
        *(f16x8*)(&s_b[0][st_off]) = wv0;
        __syncthreads();

        for (int c = 0; c < 8; ++c) {
            int b = c & 1;
            f16x8 av, wv;
            if (c < 7) {
                int cn = c + 1;
                const _Float16* asrc = (cn < 4) ? Xf : Aggf;
                const _Float16* wsrc = (cn < 4) ? Wsf : Wnf;
                int kb = (cn & 3) * 32;
                av = *(const f16x8*)(asrc + (size_t)rstage * D + kb + q * 8);
                wv = *(const f16x8*)(wsrc + (size_t)r * D + kb + q * 8);
            }
            f16x8 af[2], bf[4];
            af[0] = *(const f16x8*)(&s_a[b][a_off]);
            af[1] = *(const f16x8*)(&s_a[b][a_off + 16 * LDA]);
            #pragma unroll
            for (int j = 0; j < 4; ++j) bf[j] = *(const f16x8*)(&s_b[b][b_off + j * 16 * LDA]);
            #pragma unroll
            for (int i = 0; i < 2; ++i)
                #pragma unroll
                for (int j = 0; j < 4; ++j)
                    acc[i][j] = __builtin_amdgcn_mfma_f32_16x16x32_f16(af[i], bf[j], acc[i][j], 0, 0, 0);
            if (c < 7) {
                *(f16x8*)(&s_a[b ^ 1][st_off]) = av;
                *(f16x8*)(&s_b[b ^ 1][st_off]) = wv;
            }
            __syncthreads();
        }

        // h2 -> s_h2 (f16, + bias, no relu)
        #pragma unroll
        for (int j = 0; j < 4; ++j) {
            int col = wc * 64 + j * 16 + l15;
            float bv = bias[col];
            #pragma unroll
            for (int i = 0; i < 2; ++i) {
                int rowb = wr * 32 + i * 16 + lk * 4;
                #pragma unroll
                for (int v = 0; v < 4; ++v)
                    s_h2[(rowb + v) * LDAGG + col] = (_Float16)(acc[i][j][v] + bv);
            }
        }
    }

    // ---- phase 2: Pre = s_h2 @ P1cf^T (256 output cols) ----
    {
        int wr = w >> 2, wc = w & 3;          // wr in {0,1}: rows 64wr..+64; wc: cols 64wc..+64
        _Float16* s_flat = &s_a[0][0];        // 10240 f16 = 256 * LDA
        f32x4 acc2[4][4];
        #pragma unroll
        for (int i = 0; i < 4; ++i)
            #pragma unroll
            for (int j = 0; j < 4; ++j) acc2[i][j] = (f32x4){0.f, 0.f, 0.f, 0.f};

        for (int c2 = 0; c2 < 4; ++c2) {
            __syncthreads();   // covers s_h2 writes (c2==0) and prior s_flat reads
            #pragma unroll
            for (int e = 0; e < 2; ++e) {
                int idx = tid + e * 512;
                int o = idx >> 2, qq = idx & 3;
                *(f16x8*)(&s_flat[o * LDA + qq * 8]) =
                    *(const f16x8*)(P1cf + (size_t)o * 128 + c2 * 32 + qq * 8);
            }
            __syncthreads();
            f16x8 af[4], bf[4];
            #pragma unroll
            for (int i = 0; i < 4; ++i)
                af[i] = *(const f16x8*)(&s_h2[(wr * 64 + i * 16 + l15) * LDAGG + c2 * 32 + lk * 8]);
            #pragma unroll
            for (int j = 0; j < 4; ++j)
                bf[j] = *(const f16x8*)(&s_flat[(wc * 64 + j * 16 + l15) * LDA + lk * 8]);
            #pragma unroll
            for (int i = 0; i < 4; ++i)
                #pragma unroll
                for (int j = 0; j < 4; ++j)
                    acc2[i][j] = __builtin_amdgcn_mfma_f32_16x16x32_f16(af[i], bf[j], acc2[i][j], 0, 0, 0);
        }

        #pragma unroll
        for (int j = 0; j < 4; ++j) {
            int col = wc * 64 + j * 16 + l15;
            #pragma unroll
            for (int i = 0; i < 4; ++i) {
                int rowb = n0 + wr * 64 + i * 16 + lk * 4;
                #pragma unroll
                for (int v = 0; v < 4; ++v) {
                    int row = rowb + v;
                    if (row < n_rows)
                        Pre[(size_t)row * 256 + col] = (_Float16)acc2[i][j][v];
                }
            }
        }
    }
}

// ---------------- fused predictor: gather Pre rows -> h1 -> P2 -> P3 ----------------
__global__ __launch_bounds__(256) void k_mlp(
    const _Float16* __restrict__ Pre,
    const int* __restrict__ pos_src, const int* __restrict__ pos_dst,
    const int* __restrict__ neg_src, const int* __restrict__ neg_dst,
    const float* __restrict__ P1b,
    const _Float16* __restrict__ P2wf, const float* __restrict__ P2b,
    const float* __restrict__ P3w, const float* __restrict__ P3b,
    float* __restrict__ out, int EP) {
    __shared__ _Float16 s_h1[64 * LDH2];
    __shared__ _Float16 s_b[2][128 * LDA];
    __shared__ float s_red[64 * 2];
    __shared__ int s_node[128];
    int tid = threadIdx.x;
    int w = tid >> 6, l = tid & 63;
    int wr = w >> 1, wc = w & 1;
    int l15 = l & 15, lk = l >> 4;
    int p0 = blockIdx.x * 64;
    int twoEP = 2 * EP;

    if (tid < 128) {
        int p = p0 + (tid & 63);
        if (p >= twoEP) p = twoEP - 1;
        int node;
        if (tid < 64) node = (p < EP) ? pos_src[p] : neg_src[p - EP];
        else          node = (p < EP) ? pos_dst[p] : neg_dst[p - EP];
        s_node[tid] = node;
    }
    __syncthreads();

    #pragma unroll
    for (int e = 0; e < 4; ++e) {
        int idx = tid + e * 256;
        int pr = idx >> 4, u = idx & 15;
        int sn = s_node[pr], dn = s_node[64 + pr];
        f16x8 a = *(const f16x8*)(Pre + (size_t)sn * 256 + u * 8);
        f16x8 b = *(const f16x8*)(Pre + (size_t)dn * 256 + 128 + u * 8);
        float4 b0 = *(const float4*)(P1b + u * 8);
        float4 b1 = *(const float4*)(P1b + u * 8 + 4);
        float bb[8] = {b0.x, b0.y, b0.z, b0.w, b1.x, b1.y, b1.z, b1.w};
        f16x8 h;
        #pragma unroll
        for (int j = 0; j < 8; ++j)
            h[j] = (_Float16)fmaxf((float)a[j] + (float)b[j] + bb[j], 0.f);
        *(f16x8*)(&s_h1[pr * LDH2 + u * 8]) = h;
    }
    #pragma unroll
    for (int e = 0; e < 2; ++e) {
        int idx = tid + e * 256;
        int o = idx >> 2, q = idx & 3;
        *(f16x8*)(&s_b[0][o * LDA + q * 8]) = *(const f16x8*)(P2wf + (size_t)o * D + q * 8);
    }
    __syncthreads();

    f32x4 acc2[2][4];
    #pragma unroll
    for (int i = 0; i < 2; ++i)
        #pragma unroll
        for (int j = 0; j < 4; ++j) acc2[i][j] = (f32x4){0.f, 0.f, 0.f, 0.f};

    for (int c = 0; c < 4; ++c) {
        int b = c & 1;
        f16x8 nw[2];
        if (c < 3) {
            #pragma unroll
            for (int e = 0; e < 2; ++e) {
                int idx = tid + e * 256;
                int o = idx >> 2, q = idx & 3;
                nw[e] = *(const f16x8*)(P2wf + (size_t)o * D + (c + 1) * 32 + q * 8);
            }
        }
        f16x8 af[2], bf[4];
        af[0] = *(const f16x8*)(&s_h1[(wr * 32 + l15) * LDH2 + c * 32 + lk * 8]);
        af[1] = *(const f16x8*)(&s_h1[(wr * 32 + 16 + l15) * LDH2 + c * 32 + lk * 8]);
        #pragma unroll
        for (int j = 0; j < 4; ++j)
            bf[j] = *(const f16x8*)(&s_b[b][(wc * 64 + j * 16 + l15) * LDA + lk * 8]);
        #pragma unroll
        for (int i = 0; i < 2; ++i)
            #pragma unroll
            for (int j = 0; j < 4; ++j)
                acc2[i][j] = __builtin_amdgcn_mfma_f32_16x16x32_f16(af[i], bf[j], acc2[i][j], 0, 0, 0);
        if (c < 3) {
            #pragma unroll
            for (int e = 0; e < 2; ++e) {
                int idx = tid + e * 256;
                int o = idx >> 2, q = idx & 3;
                *(f16x8*)(&s_b[b ^ 1][o * LDA + q * 8]) = nw[e];
            }
        }
        __syncthreads();
    }

    float b2v[4], pw[4];
    #pragma unroll
    for (int j = 0; j < 4; ++j) {
        int col = wc * 64 + j * 16 + l15;
        b2v[j] = P2b[col];
        pw[j] = P3w[col];
    }
    #pragma unroll
    for (int i = 0; i < 2; ++i) {
        #pragma unroll
        for (int v = 0; v < 4; ++v) {
            float s = 0.f;
            #pragma unroll
            for (int j = 0; j < 4; ++j)
                s += fmaxf(acc2[i][j][v] + b2v[j], 0.f) * pw[j];
            s += __shfl_xor(s, 1);
            s += __shfl_xor(s, 2);
            s += __shfl_xor(s, 4);
            s += __shfl_xor(s, 8);
            if (l15 == 0)
                s_red[(wr * 32 + i * 16 + lk * 4 + v) * 2 + wc] = s;
        }
    }
    __syncthreads();
    if (tid < 64) {
        int p = p0 + tid;
        if (p < twoEP) out[p] = s_red[tid * 2] + s_red[tid * 2 + 1] + P3b[0];
    }
}

static inline size_t align_up(size_t x, size_t a) { return (x + a - 1) & ~(a - 1); }

extern "C" void kernel_launch(void* const* d_in, const int* in_sizes, int n_in,
                              void* d_out, int out_size, void* d_ws, size_t ws_size,
                              hipStream_t stream) {
    const float* x        = (const float*)d_in[0];
    const int*   edge_src = (const int*)d_in[1];
    const int*   edge_dst = (const int*)d_in[2];
    const int*   pos_src  = (const int*)d_in[3];
    const int*   pos_dst  = (const int*)d_in[4];
    const int*   neg_src  = (const int*)d_in[5];
    const int*   neg_dst  = (const int*)d_in[6];
    const float* W1n = (const float*)d_in[7];
    const float* W1s = (const float*)d_in[8];
    const float* b1  = (const float*)d_in[9];
    const float* W2n = (const float*)d_in[10];
    const float* W2s = (const float*)d_in[11];
    const float* b2  = (const float*)d_in[12];
    const float* P1w = (const float*)d_in[13];
    const float* P1b = (const float*)d_in[14];
    const float* P2w = (const float*)d_in[15];
    const float* P2b = (const float*)d_in[16];
    const float* P3w = (const float*)d_in[17];
    const float* P3b = (const float*)d_in[18];
    float* out = (float*)d_out;

    const int N = in_sizes[0] / D;
    const int E = in_sizes[1];
    const int EP = in_sizes[3];
    const int bound = (N + NR - 1) / NR;   // nodes per region (196 < 256)

    char* ws = (char*)d_ws;
    size_t off = 0;
    int* row_off = (int*)(ws + off); off = align_up(off + (size_t)(N + 1) * 4, 256);
    int* regmeta = (int*)(ws + off); off = align_up(off + (size_t)(3 * NR + 8) * 4, 256);
    int* csr     = (int*)(ws + off); off = align_up(off + (size_t)E * 4, 256);
    unsigned int* epart = (unsigned int*)(ws + off); off = align_up(off + (size_t)E * 4, 256);
    _Float16* xf   = (_Float16*)(ws + off); off = align_up(off + (size_t)N * D * 2, 256);
    _Float16* aggf = (_Float16*)(ws + off); off = align_up(off + (size_t)N * D * 2, 256);
    _Float16* h1f  = (_Float16*)(ws + off); off = align_up(off + (size_t)N * D * 2, 256);
    _Float16* Pre  = (_Float16*)(ws + off); off = align_up(off + (size_t)N * 256 * 2, 256);
    _Float16* Ws1f = (_Float16*)(ws + off); off = align_up(off + (size_t)D * D * 2, 256);
    _Float16* Wn1f = (_Float16*)(ws + off); off = align_up(off + (size_t)D * D * 2, 256);
    _Float16* Ws2f = (_Float16*)(ws + off); off = align_up(off + (size_t)D * D * 2, 256);
    _Float16* Wn2f = (_Float16*)(ws + off); off = align_up(off + (size_t)D * D * 2, 256);
    _Float16* P1cf = (_Float16*)(ws + off); off = align_up(off + (size_t)2 * D * D * 2, 256);
    _Float16* P2wf = (_Float16*)(ws + off); off = align_up(off + (size_t)D * D * 2, 256);
    (void)ws_size;

    int* region_cnt    = regmeta;               // [NR]
    int* region_base   = regmeta + NR;          // [NR+1]
    int* region_cursor = regmeta + 2 * NR + 4;  // [NR]

    const int n8 = N * D / 8;
    const int nb_x = (n8 + 255) / 256;

    // --- setup: cvt_x + cvt_weights + region histogram (one launch) ---
    hipMemsetAsync(region_cnt, 0, NR * 4, stream);
    k_setup<<<nb_x + 56 + 128, 256, 0, stream>>>(
        x, xf, n8, nb_x, W1s, W1n, W2s, W2n, P1w, P2w,
        Ws1f, Wn1f, Ws2f, Wn2f, P1cf, P2wf,
        edge_dst, region_cnt, E, bound);
    k_regbase<<<1, NR, 0, stream>>>(region_cnt, region_base, region_cursor);
    k_regpart<<<128, 256, 0, stream>>>(edge_src, edge_dst, epart, region_cursor, E, bound);
    k_rowoff_scatter<<<NR, 256, 0, stream>>>(epart, region_base, row_off, csr, N, bound);

    const int ngrid = (N + 127) / 128;
    const int pgrid = (2 * EP + 63) / 64;

    // --- layer 1 ---
    k_agg<<<(N + 15) / 16, 256, 0, stream>>>(xf, row_off, csr, aggf, N);
    k_transform<<<ngrid, 512, 0, stream>>>(xf, aggf, Ws1f, Wn1f, b1, h1f, N);
    // --- layer 2 (fused with Pre GEMM; h2 never globalized) ---
    k_agg<<<(N + 15) / 16, 256, 0, stream>>>(h1f, row_off, csr, aggf, N);
    k_transform_pre<<<ngrid, 512, 0, stream>>>(h1f, aggf, Ws2f, Wn2f, b2, P1cf, Pre, N);

    // --- predictor ---
    k_mlp<<<pgrid, 256, 0, stream>>>(Pre, pos_src, pos_dst, neg_src, neg_dst,
                                     P1b, P2wf, P2b, P3w, P3b, out, EP);
}